// Round 14
// baseline (157.073 us; speedup 1.0000x reference)
//
#include <hip/hip_runtime.h>

// Fused double-softmax attention, fp32 in/out, f16 MFMA for QK^T and PV.
// B=4 H=8 S=1024 D=64. Outputs: context [B,H,S,D] then attn [B,H,S,S].
// R14 = R13 + Phase-B loads for BOTH rows hoisted BEFORE Phase A's
// reduction+barrier (24 nontemporal loads in flight, hidden behind barrier;
// one latency hit per block instead of two per wave).
typedef _Float16 f16;
typedef _Float16 f16x8 __attribute__((ext_vector_type(8)));
typedef _Float16 f16x4 __attribute__((ext_vector_type(4)));
typedef float f32x4 __attribute__((ext_vector_type(4)));
typedef int   i32x4 __attribute__((ext_vector_type(4)));

constexpr int B_ = 4, H_ = 8, S_ = 1024, D_ = 64;
constexpr int BQ = 16;        // q rows per block
constexpr int NT = 512;       // 8 waves
constexpr int KC = 128;       // k per chunk (one 16-col tile per wave)
constexpr int QH_LD = 72;     // Qh row stride in f16
constexpr int SC_LD = 1032;   // sch row stride in f16
constexpr float LOG2E = 1.44269504f;

__device__ __forceinline__ float wred(float v) {
#pragma unroll
  for (int off = 32; off > 0; off >>= 1) v += __shfl_xor(v, off);
  return v;
}

__global__ __launch_bounds__(NT)
void fused_attn(const float* __restrict__ Q, const float* __restrict__ K,
                const float* __restrict__ V, const int* __restrict__ mask,
                const float* __restrict__ adj, const float* __restrict__ dist,
                const float* __restrict__ cw, const float* __restrict__ cb,
                float* __restrict__ outC, float* __restrict__ outA)
{
  __shared__ __align__(16) f16 Qh[BQ * QH_LD];     // 2.3 KB
  __shared__ __align__(16) f16 sch[BQ * SC_LD];    // 33.0 KB (C-scratch reuse)
  __shared__ float rs1w[8][16];
  __shared__ float rinv2[BQ];

  const int tid = threadIdx.x;
  // bijective XCD swizzle: 2048 blocks = 8 XCDs x 256 (4 heads per XCD)
  const int sw = (blockIdx.x & 7) * 256 + (blockIdx.x >> 3);
  const int qt = sw & 63;
  const int bh = sw >> 6;
  const int q0 = qt * BQ;
  const int wv = tid >> 6;    // wave 0..7
  const int ln = tid & 63;
  const int lg = ln >> 4;     // lane group 0..3
  const int li = ln & 15;

  const float* Qp = Q + ((size_t)bh * S_ + q0) * D_;
  const float* Kp = K + (size_t)bh * S_ * D_;
  const float* Vp = V + (size_t)bh * S_ * D_;
  const size_t rb = ((size_t)bh * S_ + q0) * S_;

  // stage Q tile -> f16
  if (tid < 256) {
    const int q = tid >> 4, c4 = (tid & 15) << 2;
    float4 v = *(const float4*)(Qp + q * D_ + c4);
    f16* d = &Qh[q * QH_LD + c4];
    d[0] = (f16)v.x; d[1] = (f16)v.y; d[2] = (f16)v.z; d[3] = (f16)v.w;
  }
  const float w0 = cw[0], w1 = cw[1], w2 = cw[2], bb = cb[0];
  __syncthreads();                                  // (1)

  // hoist Q fragments (A operand; lane li = q-row li, k = s*32 + lg*8)
  f16x8 aq0 = *(const f16x8*)&Qh[li * QH_LD + 0 * 32 + lg * 8];
  f16x8 aq1 = *(const f16x8*)&Qh[li * QH_LD + 1 * 32 + lg * 8];

  // ===== Phase A: UNMASKED e = exp(QK^T/8) via MFMA; K straight from global ==
  const int n0 = wv * 16;
  float rs[4] = {0.f, 0.f, 0.f, 0.f};
#pragma unroll 2
  for (int c = 0; c < 8; ++c) {
    const int kg = c * KC + n0 + li;
    const float* Kr = Kp + (size_t)kg * D_ + lg * 8;
    const float4 ka = *(const float4*)(Kr + 0);
    const float4 kb = *(const float4*)(Kr + 4);
    const float4 kc2 = *(const float4*)(Kr + 32);
    const float4 kd = *(const float4*)(Kr + 36);
    f16x8 b0, b1;
    b0[0] = (f16)ka.x; b0[1] = (f16)ka.y; b0[2] = (f16)ka.z; b0[3] = (f16)ka.w;
    b0[4] = (f16)kb.x; b0[5] = (f16)kb.y; b0[6] = (f16)kb.z; b0[7] = (f16)kb.w;
    b1[0] = (f16)kc2.x; b1[1] = (f16)kc2.y; b1[2] = (f16)kc2.z; b1[3] = (f16)kc2.w;
    b1[4] = (f16)kd.x; b1[5] = (f16)kd.y; b1[6] = (f16)kd.z; b1[7] = (f16)kd.w;
    f32x4 acc = {0.f, 0.f, 0.f, 0.f};
    acc = __builtin_amdgcn_mfma_f32_16x16x32_f16(aq0, b0, acc, 0, 0, 0);
    acc = __builtin_amdgcn_mfma_f32_16x16x32_f16(aq1, b1, acc, 0, 0, 0);
#pragma unroll
    for (int r = 0; r < 4; ++r) {            // D[m][n]: m=lg*4+r, n=li
      const int m = lg * 4 + r;
      const f16 ef = (f16)exp2f(acc[r] * (0.125f * LOG2E));
      sch[m * SC_LD + kg] = ef;
      rs[r] += (float)ef;                    // rounded full-row sum
    }
  }

  // ===== Phase B loads for BOTH rows, issued EARLY (hidden behind barrier) ===
  const int k0 = ln * 4;
  const int qB0 = 2 * wv, qB1 = 2 * wv + 1;
  const size_t base0 = rb + (size_t)qB0 * S_;
  const size_t base1 = rb + (size_t)qB1 * S_;
  const i32x4 m00 = __builtin_nontemporal_load((const i32x4*)(mask + base0 + k0 + 0));
  const i32x4 m01 = __builtin_nontemporal_load((const i32x4*)(mask + base0 + k0 + 256));
  const i32x4 m02 = __builtin_nontemporal_load((const i32x4*)(mask + base0 + k0 + 512));
  const i32x4 m03 = __builtin_nontemporal_load((const i32x4*)(mask + base0 + k0 + 768));
  const i32x4 m10 = __builtin_nontemporal_load((const i32x4*)(mask + base1 + k0 + 0));
  const i32x4 m11 = __builtin_nontemporal_load((const i32x4*)(mask + base1 + k0 + 256));
  const i32x4 m12 = __builtin_nontemporal_load((const i32x4*)(mask + base1 + k0 + 512));
  const i32x4 m13 = __builtin_nontemporal_load((const i32x4*)(mask + base1 + k0 + 768));
  const f32x4 d00 = __builtin_nontemporal_load((const f32x4*)(dist + base0 + k0 + 0));
  const f32x4 d01 = __builtin_nontemporal_load((const f32x4*)(dist + base0 + k0 + 256));
  const f32x4 d02 = __builtin_nontemporal_load((const f32x4*)(dist + base0 + k0 + 512));
  const f32x4 d03 = __builtin_nontemporal_load((const f32x4*)(dist + base0 + k0 + 768));
  const f32x4 d10 = __builtin_nontemporal_load((const f32x4*)(dist + base1 + k0 + 0));
  const f32x4 d11 = __builtin_nontemporal_load((const f32x4*)(dist + base1 + k0 + 256));
  const f32x4 d12 = __builtin_nontemporal_load((const f32x4*)(dist + base1 + k0 + 512));
  const f32x4 d13 = __builtin_nontemporal_load((const f32x4*)(dist + base1 + k0 + 768));
  const f32x4 a00 = __builtin_nontemporal_load((const f32x4*)(adj + base0 + k0 + 0));
  const f32x4 a01 = __builtin_nontemporal_load((const f32x4*)(adj + base0 + k0 + 256));
  const f32x4 a02 = __builtin_nontemporal_load((const f32x4*)(adj + base0 + k0 + 512));
  const f32x4 a03 = __builtin_nontemporal_load((const f32x4*)(adj + base0 + k0 + 768));
  const f32x4 a10 = __builtin_nontemporal_load((const f32x4*)(adj + base1 + k0 + 0));
  const f32x4 a11 = __builtin_nontemporal_load((const f32x4*)(adj + base1 + k0 + 256));
  const f32x4 a12 = __builtin_nontemporal_load((const f32x4*)(adj + base1 + k0 + 512));
  const f32x4 a13 = __builtin_nontemporal_load((const f32x4*)(adj + base1 + k0 + 768));
  __builtin_amdgcn_sched_barrier(0);

  // Phase A reduction (overlaps the in-flight loads)
#pragma unroll
  for (int r = 0; r < 4; ++r) {              // reduce over 16 lanes per group
    rs[r] += __shfl_xor(rs[r], 1); rs[r] += __shfl_xor(rs[r], 2);
    rs[r] += __shfl_xor(rs[r], 4); rs[r] += __shfl_xor(rs[r], 8);
  }
  if (li == 0) {
#pragma unroll
    for (int r = 0; r < 4; ++r) rs1w[wv][lg * 4 + r] = rs[r];
  }
  __syncthreads();                                  // (2) sch + rs1w visible

  // ===== Phase B compute: both rows ==========================================
  {
    const f16x4 ef00 = *(const f16x4*)&sch[qB0 * SC_LD + k0 + 0];
    const f16x4 ef01 = *(const f16x4*)&sch[qB0 * SC_LD + k0 + 256];
    const f16x4 ef02 = *(const f16x4*)&sch[qB0 * SC_LD + k0 + 512];
    const f16x4 ef03 = *(const f16x4*)&sch[qB0 * SC_LD + k0 + 768];
    const f16x4 ef10 = *(const f16x4*)&sch[qB1 * SC_LD + k0 + 0];
    const f16x4 ef11 = *(const f16x4*)&sch[qB1 * SC_LD + k0 + 256];
    const f16x4 ef12 = *(const f16x4*)&sch[qB1 * SC_LD + k0 + 512];
    const f16x4 ef13 = *(const f16x4*)&sch[qB1 * SC_LD + k0 + 768];
    float tq0 = 0.f, tq1 = 0.f;
#pragma unroll
    for (int w = 0; w < 8; ++w) {                   // uniform broadcast reads
      tq0 += rs1w[w][qB0];
      tq1 += rs1w[w][qB1];
    }
#define CORR4(MV, EF)                                                         \
    ((MV[0] ? (float)EF[0] : 0.f) + (MV[1] ? (float)EF[1] : 0.f) +            \
     (MV[2] ? (float)EF[2] : 0.f) + (MV[3] ? (float)EF[3] : 0.f))
    float corr0 = CORR4(m00, ef00) + CORR4(m01, ef01) +
                  CORR4(m02, ef02) + CORR4(m03, ef03);
    float corr1 = CORR4(m10, ef10) + CORR4(m11, ef11) +
                  CORR4(m12, ef12) + CORR4(m13, ef13);
#undef CORR4
    corr0 = wred(corr0);
    corr1 = wred(corr1);
    const float i10 = 1.f / (tq0 - corr0);
    const float i11 = 1.f / (tq1 - corr1);
    const float W1 = w1 * LOG2E, W2 = w2 * LOG2E, BBL = bb * LOG2E;
    f16x4 af00, af01, af02, af03, af10, af11, af12, af13;
    float s20 = 0.f, s21 = 0.f;
#define CSM(AF, MV, DV, AV, EF, W0, S2)                                       \
    {                                                                         \
      const float t0 = fmaf(W0, (float)EF[0], fmaf(W1, DV[0], fmaf(W2, AV[0], BBL))); \
      const float t1 = fmaf(W0, (float)EF[1], fmaf(W1, DV[1], fmaf(W2, AV[1], BBL))); \
      const float t2 = fmaf(W0, (float)EF[2], fmaf(W1, DV[2], fmaf(W2, AV[2], BBL))); \
      const float t3 = fmaf(W0, (float)EF[3], fmaf(W1, DV[3], fmaf(W2, AV[3], BBL))); \
      const float a0 = MV[0] ? 0.f : exp2f(t0);                               \
      const float a1 = MV[1] ? 0.f : exp2f(t1);                               \
      const float a2 = MV[2] ? 0.f : exp2f(t2);                               \
      const float a3 = MV[3] ? 0.f : exp2f(t3);                               \
      AF[0] = (f16)a0; AF[1] = (f16)a1; AF[2] = (f16)a2; AF[3] = (f16)a3;     \
      S2 += a0 + a1 + a2 + a3;                                                \
    }
    const float W00 = w0 * i10 * LOG2E;
    const float W01 = w0 * i11 * LOG2E;
    CSM(af00, m00, d00, a00, ef00, W00, s20)
    CSM(af01, m01, d01, a01, ef01, W00, s20)
    CSM(af02, m02, d02, a02, ef02, W00, s20)
    CSM(af03, m03, d03, a03, ef03, W00, s20)
    CSM(af10, m10, d10, a10, ef10, W01, s21)
    CSM(af11, m11, d11, a11, ef11, W01, s21)
    CSM(af12, m12, d12, a12, ef12, W01, s21)
    CSM(af13, m13, d13, a13, ef13, W01, s21)
#undef CSM
    *(f16x4*)&sch[qB0 * SC_LD + k0 + 0]   = af00;
    *(f16x4*)&sch[qB0 * SC_LD + k0 + 256] = af01;
    *(f16x4*)&sch[qB0 * SC_LD + k0 + 512] = af02;
    *(f16x4*)&sch[qB0 * SC_LD + k0 + 768] = af03;
    *(f16x4*)&sch[qB1 * SC_LD + k0 + 0]   = af10;
    *(f16x4*)&sch[qB1 * SC_LD + k0 + 256] = af11;
    *(f16x4*)&sch[qB1 * SC_LD + k0 + 512] = af12;
    *(f16x4*)&sch[qB1 * SC_LD + k0 + 768] = af13;
    s20 = wred(s20);
    s21 = wred(s21);
    const float i20 = 1.f / s20;
    const float i21 = 1.f / s21;
    if (ln == 0) { rinv2[qB0] = i20; rinv2[qB1] = i21; }
    f32x4 o;
#define OUTW(AF, I2, PTR)                                                     \
    o[0] = (float)AF[0] * I2; o[1] = (float)AF[1] * I2;                       \
    o[2] = (float)AF[2] * I2; o[3] = (float)AF[3] * I2;                       \
    __builtin_nontemporal_store(o, (f32x4*)(PTR));
    OUTW(af00, i20, outA + base0 + k0 + 0)
    OUTW(af01, i20, outA + base0 + k0 + 256)
    OUTW(af02, i20, outA + base0 + k0 + 512)
    OUTW(af03, i20, outA + base0 + k0 + 768)
    OUTW(af10, i21, outA + base1 + k0 + 0)
    OUTW(af11, i21, outA + base1 + k0 + 256)
    OUTW(af12, i21, outA + base1 + k0 + 512)
    OUTW(af13, i21, outA + base1 + k0 + 768)
#undef OUTW
  }
  __syncthreads();                                  // (3) sch aw-values visible

  // ===== Phase C: ctx = P(f16) x V(f16); V^T fragments straight from global ==
  const int ntile = wv >> 1;
  const int spair = (wv & 1) * 2;
  const int d0 = ntile * 16 + li;
  f32x4 cacc = {0.f, 0.f, 0.f, 0.f};
#pragma unroll 2
  for (int c = 0; c < 8; ++c) {
#pragma unroll
    for (int u = 0; u < 2; ++u) {
      const int s = spair + u;
      const float* Vc = Vp + (size_t)(c * KC + s * 32 + lg * 8) * D_ + d0;
      f16x8 bfr;
#pragma unroll
      for (int j = 0; j < 8; ++j) bfr[j] = (f16)Vc[(size_t)j * D_];
      f16x8 a = *(const f16x8*)&sch[li * SC_LD + c * KC + s * 32 + lg * 8];
      cacc = __builtin_amdgcn_mfma_f32_16x16x32_f16(a, bfr, cacc, 0, 0, 0);
    }
  }
  __syncthreads();                                  // (4) all sch reads done
  float* fscr = reinterpret_cast<float*>(sch);      // alias 8 KB scratch
  *(f32x4*)&fscr[tid * 4] = cacc;
  __syncthreads();                                  // (5)
  if (tid < 256) {                    // combine wave pairs, scale, write ctx
    const int t = tid >> 6, l2 = tid & 63;
    const int g2 = l2 >> 4, n = l2 & 15;
    f32x4 p  = *(const f32x4*)&fscr[((2 * t) * 64 + l2) * 4];
    f32x4 p2 = *(const f32x4*)&fscr[((2 * t + 1) * 64 + l2) * 4];
#pragma unroll
    for (int r = 0; r < 4; ++r) {
      const int m = g2 * 4 + r;
      outC[((size_t)bh * S_ + q0 + m) * D_ + t * 16 + n] = (p[r] + p2[r]) * rinv2[m];
    }
  }
}

extern "C" void kernel_launch(void* const* d_in, const int* in_sizes, int n_in,
                              void* d_out, int out_size, void* d_ws, size_t ws_size,
                              hipStream_t stream) {
  const float* Q    = (const float*)d_in[0];
  const float* K    = (const float*)d_in[1];
  const float* V    = (const float*)d_in[2];
  const int*   mask = (const int*)  d_in[3];
  const float* adj  = (const float*)d_in[4];
  const float* dist = (const float*)d_in[5];
  const float* cw   = (const float*)d_in[6];
  const float* cb   = (const float*)d_in[7];

  float* outC = (float*)d_out;                                   // [B,H,S,D]
  float* outA = outC + (size_t)B_ * H_ * S_ * D_;                // [B,H,S,S]

  fused_attn<<<dim3(B_ * H_ * (S_ / BQ)), NT, 0, stream>>>(
      Q, K, V, mask, adj, dist, cw, cb, outC, outA);
}